// Round 6
// baseline (659.402 us; speedup 1.0000x reference)
//
#include <hip/hip_runtime.h>
#include <math.h>

#define NN 100000
#define NE 1600000
#define ETOT (NE + NN)
#define HEADS 8
#define NCLS 40
#define SLOPE 0.2f

#define SCAN_B 512
#define NBLK ((NN + SCAN_B - 1) / SCAN_B)   // 196

typedef unsigned short ushort_t;
typedef __attribute__((ext_vector_type(8))) short short8;
typedef __attribute__((ext_vector_type(8))) _Float16 half8;
typedef __attribute__((ext_vector_type(4))) float f32x4;

static __device__ __forceinline__ ushort_t f2bf(float f) {
    unsigned u = __float_as_uint(f);
    unsigned r = (u + 0x7FFFu + ((u >> 16) & 1u)) >> 16;   // RNE
    return (ushort_t)r;
}
static __device__ __forceinline__ float bf2f(ushort_t b) {
    return __uint_as_float(((unsigned)b) << 16);
}
static __device__ __forceinline__ ushort_t f2h(float f) {
    _Float16 h = (_Float16)f;
    return __builtin_bit_cast(ushort_t, h);
}
static __device__ __forceinline__ float h2f(ushort_t u) {
    return (float)__builtin_bit_cast(_Float16, u);
}

// ----------------- CSR build -----------------
__global__ void k_deg_init(int* __restrict__ deg) {
    int i = blockIdx.x * blockDim.x + threadIdx.x;
    if (i < NN) deg[i] = 1;  // self loop
}

__global__ void k_hist(const int* __restrict__ ei, int* __restrict__ deg) {
    int e = blockIdx.x * blockDim.x + threadIdx.x;
    if (e < NE) {
        unsigned d = (unsigned)ei[NE + e];
        if (d < NN) atomicAdd(&deg[d], 1);
    }
}

__global__ void k_blocksum(const int* __restrict__ deg, int* __restrict__ bsum) {
    __shared__ int sh[SCAN_B];
    int b = blockIdx.x;
    int i = b * SCAN_B + threadIdx.x;
    sh[threadIdx.x] = (i < NN) ? deg[i] : 0;
    __syncthreads();
    for (int s = SCAN_B / 2; s > 0; s >>= 1) {
        if (threadIdx.x < s) sh[threadIdx.x] += sh[threadIdx.x + s];
        __syncthreads();
    }
    if (threadIdx.x == 0) bsum[b] = sh[0];
}

__global__ void k_scan_bsums(int* __restrict__ bsum, int nblk) {
    __shared__ int sh[1024];
    int t = threadIdx.x;
    int v = (t < nblk) ? bsum[t] : 0;
    sh[t] = v;
    __syncthreads();
    for (int o = 1; o < 1024; o <<= 1) {
        int add = (t >= o) ? sh[t - o] : 0;
        __syncthreads();
        sh[t] += add;
        __syncthreads();
    }
    if (t < nblk) bsum[t] = sh[t] - v;  // exclusive
}

__global__ void k_offsets(const int* __restrict__ deg, const int* __restrict__ bsum,
                          int* __restrict__ offset, int* __restrict__ cursor,
                          int* __restrict__ csr_src) {
    __shared__ int sh[SCAN_B];
    int b = blockIdx.x, t = threadIdx.x;
    int i = b * SCAN_B + t;
    int v = (i < NN) ? deg[i] : 0;
    sh[t] = v;
    __syncthreads();
    for (int o = 1; o < SCAN_B; o <<= 1) {
        int add = (t >= o) ? sh[t - o] : 0;
        __syncthreads();
        sh[t] += add;
        __syncthreads();
    }
    if (i < NN) {
        int excl = sh[t] - v + bsum[b];
        offset[i] = excl;
        cursor[i] = excl + 1;
        csr_src[excl] = i;  // pre-place self loop
    }
}

__global__ void k_scatter(const int* __restrict__ ei, int* __restrict__ cursor,
                          int* __restrict__ csr_src) {
    int e = blockIdx.x * blockDim.x + threadIdx.x;
    if (e < NE) {
        unsigned d = (unsigned)ei[NE + e];
        unsigned s = (unsigned)ei[e];
        if (d < NN && s < NN) {
            int pos = atomicAdd(&cursor[d], 1);
            csr_src[pos] = (int)s;
        }
    }
}

// ----------------- split W1 into bf16 hi/lo, transposed [n][k] -------------
__global__ void k_splitW(const float* __restrict__ W, ushort_t* __restrict__ Wht,
                         ushort_t* __restrict__ Wlt) {
    int k = blockIdx.x;          // 256 blocks
    int n = threadIdx.x;         // 256 threads
    float v = W[k * 256 + n];
    ushort_t hi = f2bf(v);
    ushort_t lo = f2bf(v - bf2f(hi));
    Wht[n * 256 + k] = hi;
    Wlt[n * 256 + k] = lo;
}

// ----------------- split W2 [256][40] -> padded transposed [48][256] f16 ---
__global__ void k_splitW2(const float* __restrict__ W, ushort_t* __restrict__ Wht,
                          ushort_t* __restrict__ Wlt) {
    int n = blockIdx.x;          // 48 blocks
    int k = threadIdx.x;         // 256 threads
    float v = (n < NCLS) ? W[k * NCLS + n] : 0.f;
    ushort_t hi = f2h(v);
    ushort_t lo = f2h(v - h2f(hi));
    Wht[n * 256 + k] = hi;
    Wlt[n * 256 + k] = lo;
}

// ----------------- GEMM1 (MFMA split-bf16): h1h(f16) = x @ W1; fused alphas
#define LSTR 40   // ushorts per LDS row
__global__ __launch_bounds__(256) void k_gemm1(const float* __restrict__ A,
                                               const ushort_t* __restrict__ Bht,
                                               const ushort_t* __restrict__ Blt,
                                               const float* __restrict__ attS,
                                               const float* __restrict__ attD,
                                               ushort_t* __restrict__ h1h,
                                               float* __restrict__ as1,
                                               float* __restrict__ ad1) {
    __shared__ ushort_t Ah[128 * LSTR];
    __shared__ ushort_t Al[128 * LSTR];
    __shared__ ushort_t Bh[128 * LSTR];
    __shared__ ushort_t Bl[128 * LSTR];

    int bx = blockIdx.x & 1;
    int by = blockIdx.x >> 1;
    int row0 = by * 128, col0 = bx * 128;
    int t = threadIdx.x;
    int w = t >> 6, lane = t & 63;
    int lr = lane & 15, lg = lane >> 4;
    int R0 = (w >> 1) * 64, C0 = (w & 1) * 64;

    int ar = t >> 1, ah = t & 1;          // A: row, k-half(16 f32)
    int gr_a = row0 + ar;

    f32x4 acc[4][4];
#pragma unroll
    for (int i = 0; i < 4; i++)
#pragma unroll
        for (int j = 0; j < 4; j++) acc[i][j] = (f32x4){0.f, 0.f, 0.f, 0.f};

    for (int it = 0; it < 8; it++) {
        int k0 = it * 32;
        __syncthreads();
        // ---- stage A (convert f32 -> bf16 hi/lo) ----
        {
            float f[16];
            if (gr_a < NN) {
                const float* ap = A + (size_t)gr_a * 256 + k0 + ah * 16;
#pragma unroll
                for (int i = 0; i < 4; i++) {
                    float4 v = *reinterpret_cast<const float4*>(ap + i * 4);
                    f[i * 4 + 0] = v.x; f[i * 4 + 1] = v.y; f[i * 4 + 2] = v.z; f[i * 4 + 3] = v.w;
                }
            } else {
#pragma unroll
                for (int i = 0; i < 16; i++) f[i] = 0.f;
            }
            unsigned hw[8], lw[8];
#pragma unroll
            for (int i = 0; i < 8; i++) {
                ushort_t h0 = f2bf(f[2 * i]), h1v = f2bf(f[2 * i + 1]);
                ushort_t l0 = f2bf(f[2 * i] - bf2f(h0)), l1 = f2bf(f[2 * i + 1] - bf2f(h1v));
                hw[i] = (unsigned)h0 | ((unsigned)h1v << 16);
                lw[i] = (unsigned)l0 | ((unsigned)l1 << 16);
            }
            uint4* dsth = reinterpret_cast<uint4*>(&Ah[ar * LSTR + ah * 16]);
            dsth[0] = make_uint4(hw[0], hw[1], hw[2], hw[3]);
            dsth[1] = make_uint4(hw[4], hw[5], hw[6], hw[7]);
            uint4* dstl = reinterpret_cast<uint4*>(&Al[ar * LSTR + ah * 16]);
            dstl[0] = make_uint4(lw[0], lw[1], lw[2], lw[3]);
            dstl[1] = make_uint4(lw[4], lw[5], lw[6], lw[7]);
        }
        // ---- stage B (pre-split, pre-transposed [n][k]) ----
        {
            int bn = t >> 1, bh2 = t & 1;
            const uint4* sh = reinterpret_cast<const uint4*>(Bht + (size_t)(col0 + bn) * 256 + k0 + bh2 * 16);
            const uint4* sl = reinterpret_cast<const uint4*>(Blt + (size_t)(col0 + bn) * 256 + k0 + bh2 * 16);
            uint4* dh = reinterpret_cast<uint4*>(&Bh[bn * LSTR + bh2 * 16]);
            uint4* dl = reinterpret_cast<uint4*>(&Bl[bn * LSTR + bh2 * 16]);
            dh[0] = sh[0]; dh[1] = sh[1];
            dl[0] = sl[0]; dl[1] = sl[1];
        }
        __syncthreads();
        // ---- fragments + MFMA ----
        short8 bhf[4], blf[4];
#pragma unroll
        for (int ni = 0; ni < 4; ni++) {
            int c = C0 + ni * 16 + lr;
            bhf[ni] = *reinterpret_cast<const short8*>(&Bh[c * LSTR + lg * 8]);
            blf[ni] = *reinterpret_cast<const short8*>(&Bl[c * LSTR + lg * 8]);
        }
#pragma unroll
        for (int mi = 0; mi < 4; mi++) {
            int r = R0 + mi * 16 + lr;
            short8 ahf = *reinterpret_cast<const short8*>(&Ah[r * LSTR + lg * 8]);
            short8 alf = *reinterpret_cast<const short8*>(&Al[r * LSTR + lg * 8]);
#pragma unroll
            for (int ni = 0; ni < 4; ni++) {
                acc[mi][ni] = __builtin_amdgcn_mfma_f32_16x16x32_bf16(ahf, bhf[ni], acc[mi][ni], 0, 0, 0);
                acc[mi][ni] = __builtin_amdgcn_mfma_f32_16x16x32_bf16(alf, bhf[ni], acc[mi][ni], 0, 0, 0);
                acc[mi][ni] = __builtin_amdgcn_mfma_f32_16x16x32_bf16(ahf, blf[ni], acc[mi][ni], 0, 0, 0);
            }
        }
    }

    // ---- epilogue: f16 store + fused alpha dots ----
    int cn[4];
    float sa[4], da[4];
#pragma unroll
    for (int ni = 0; ni < 4; ni++) {
        cn[ni] = col0 + C0 + ni * 16 + lr;
        sa[ni] = attS[cn[ni]];
        da[ni] = attD[cn[ni]];
    }
    int head0 = (col0 + C0) >> 5;
#pragma unroll
    for (int mi = 0; mi < 4; mi++) {
#pragma unroll
        for (int r = 0; r < 4; r++) {
            int gr = row0 + R0 + mi * 16 + lg * 4 + r;
            float v0 = acc[mi][0][r], v1 = acc[mi][1][r];
            float v2 = acc[mi][2][r], v3 = acc[mi][3][r];
            float ps0 = v0 * sa[0] + v1 * sa[1];
            float pd0 = v0 * da[0] + v1 * da[1];
            float ps1 = v2 * sa[2] + v3 * sa[3];
            float pd1 = v2 * da[2] + v3 * da[3];
#pragma unroll
            for (int m = 1; m <= 8; m <<= 1) {
                ps0 += __shfl_xor(ps0, m);
                pd0 += __shfl_xor(pd0, m);
                ps1 += __shfl_xor(ps1, m);
                pd1 += __shfl_xor(pd1, m);
            }
            if (gr < NN) {
                if (lr == 0) {
                    as1[gr * 8 + head0] = ps0;
                    ad1[gr * 8 + head0] = pd0;
                    as1[gr * 8 + head0 + 1] = ps1;
                    ad1[gr * 8 + head0 + 1] = pd1;
                }
                ushort_t* hp = h1h + (size_t)gr * 256;
                hp[cn[0]] = f2h(v0);
                hp[cn[1]] = f2h(v1);
                hp[cn[2]] = f2h(v2);
                hp[cn[3]] = f2h(v3);
            }
        }
    }
}

// ----------------- softmax stats pass, layer 1: one wave/node --------------
__global__ __launch_bounds__(256) void k_soft1(const int* __restrict__ csr_src,
                                               const int* __restrict__ offset,
                                               const int* __restrict__ deg,
                                               const float* __restrict__ as1,
                                               const float* __restrict__ ad1,
                                               float* __restrict__ m1,
                                               float* __restrict__ di1) {
    int wave = (blockIdx.x * blockDim.x + threadIdx.x) >> 6;
    int lane = threadIdx.x & 63;
    if (wave >= NN) return;
    int d = wave;
    int sub = lane >> 3, h = lane & 7;
    float ad = ad1[d * 8 + h];
    int beg = offset[d], cnt = deg[d];
    float m = -1e30f, s = 0.f;
    for (int j = sub; j < cnt; j += 8) {
        int src = csr_src[beg + j];
        float e = as1[src * 8 + h] + ad;
        e = (e > 0.f) ? e : SLOPE * e;
        float mn = fmaxf(m, e);
        s = s * __expf(m - mn) + __expf(e - mn);
        m = mn;
    }
#pragma unroll
    for (int mask = 8; mask <= 32; mask <<= 1) {
        float mo = __shfl_xor(m, mask);
        float so = __shfl_xor(s, mask);
        float mn = fmaxf(m, mo);
        s = s * __expf(m - mn) + so * __expf(mo - mn);
        m = mn;
    }
    if (lane < 8) {
        m1[d * 8 + lane] = m;
        di1[d * 8 + lane] = 1.f / (s + 1e-16f);
    }
}

// ----------------- aggregate pass, layer 1 (no serial chain, f16 gather) ---
__global__ __launch_bounds__(256) void k_agg1(const int* __restrict__ csr_src,
                                              const int* __restrict__ offset,
                                              const int* __restrict__ deg,
                                              const ushort_t* __restrict__ h1h,
                                              const float* __restrict__ as1,
                                              const float* __restrict__ ad1,
                                              const float* __restrict__ m1,
                                              const float* __restrict__ di1,
                                              const float* __restrict__ bias1,
                                              ushort_t* __restrict__ h2h) {
    int wave = (blockIdx.x * blockDim.x + threadIdx.x) >> 6;
    int lane = threadIdx.x & 63;
    if (wave >= NN) return;
    int d = wave;
    int h = lane >> 3;
    int f0 = lane * 4;
    float ad = ad1[d * 8 + h];
    float m = m1[d * 8 + h];
    float dinv = di1[d * 8 + h];
    int beg = offset[d], cnt = deg[d];
    float ax = 0.f, ay = 0.f, az = 0.f, aw = 0.f;
#pragma unroll 4
    for (int j = 0; j < cnt; j++) {
        int s = csr_src[beg + j];
        float e = as1[s * 8 + h] + ad;
        e = (e > 0.f) ? e : SLOPE * e;
        float p = __expf(e - m);
        ushort4 hv = *reinterpret_cast<const ushort4*>(h1h + (size_t)s * 256 + f0);
        ax += p * (float)__builtin_bit_cast(_Float16, hv.x);   // v_fma_mix
        ay += p * (float)__builtin_bit_cast(_Float16, hv.y);
        az += p * (float)__builtin_bit_cast(_Float16, hv.z);
        aw += p * (float)__builtin_bit_cast(_Float16, hv.w);
    }
    float4 b = *reinterpret_cast<const float4*>(bias1 + f0);
    float vx = ax * dinv + b.x;
    float vy = ay * dinv + b.y;
    float vz = az * dinv + b.z;
    float vw = aw * dinv + b.w;
    vx = (vx > 0.f) ? vx : expm1f(vx);
    vy = (vy > 0.f) ? vy : expm1f(vy);
    vz = (vz > 0.f) ? vz : expm1f(vz);
    vw = (vw > 0.f) ? vw : expm1f(vw);
    ushort4 o;
    o.x = f2h(vx); o.y = f2h(vy); o.z = f2h(vz); o.w = f2h(vw);
    *reinterpret_cast<ushort4*>(h2h + (size_t)d * 256 + f0) = o;
}

// ----------------- GEMM2 (MFMA f16): hh(f16) = h2h @ W2; fused alpha2 ------
__global__ __launch_bounds__(256) void k_gemm2(const ushort_t* __restrict__ A,
                                               const ushort_t* __restrict__ Bht,
                                               const ushort_t* __restrict__ Blt,
                                               const float* __restrict__ attS,
                                               const float* __restrict__ attD,
                                               ushort_t* __restrict__ hh,
                                               float* __restrict__ as2,
                                               float* __restrict__ ad2) {
    __shared__ ushort_t Ash[128 * LSTR];
    __shared__ ushort_t Bh[48 * LSTR];
    __shared__ ushort_t Bl[48 * LSTR];
    int row0 = blockIdx.x * 128;
    int t = threadIdx.x;
    int w = t >> 6, lane = t & 63;
    int lr = lane & 15, lg = lane >> 4;
    int R0 = w * 32;

    f32x4 acc[2][3];
#pragma unroll
    for (int i = 0; i < 2; i++)
#pragma unroll
        for (int j = 0; j < 3; j++) acc[i][j] = (f32x4){0.f, 0.f, 0.f, 0.f};

    for (int it = 0; it < 8; it++) {
        int k0 = it * 32;
        __syncthreads();
        // stage A: 128 rows x 32 ushorts = 512 uint4 chunks
#pragma unroll
        for (int i = 0; i < 2; i++) {
            int chunk = t + i * 256;
            int r = chunk >> 2, part = chunk & 3;
            int gr = row0 + r;
            uint4 v = make_uint4(0u, 0u, 0u, 0u);
            if (gr < NN) v = *reinterpret_cast<const uint4*>(A + (size_t)gr * 256 + k0 + part * 8);
            *reinterpret_cast<uint4*>(&Ash[r * LSTR + part * 8]) = v;
        }
        // stage B: 48 rows x 32 ushorts = 192 uint4 chunks
        if (t < 192) {
            int bn = t >> 2, part = t & 3;
            *reinterpret_cast<uint4*>(&Bh[bn * LSTR + part * 8]) =
                *reinterpret_cast<const uint4*>(Bht + (size_t)bn * 256 + k0 + part * 8);
            *reinterpret_cast<uint4*>(&Bl[bn * LSTR + part * 8]) =
                *reinterpret_cast<const uint4*>(Blt + (size_t)bn * 256 + k0 + part * 8);
        }
        __syncthreads();
        half8 bhf[3], blf[3];
#pragma unroll
        for (int ni = 0; ni < 3; ni++) {
            int c = ni * 16 + lr;
            bhf[ni] = *reinterpret_cast<const half8*>(&Bh[c * LSTR + lg * 8]);
            blf[ni] = *reinterpret_cast<const half8*>(&Bl[c * LSTR + lg * 8]);
        }
#pragma unroll
        for (int mi = 0; mi < 2; mi++) {
            int r = R0 + mi * 16 + lr;
            half8 af = *reinterpret_cast<const half8*>(&Ash[r * LSTR + lg * 8]);
#pragma unroll
            for (int ni = 0; ni < 3; ni++) {
                acc[mi][ni] = __builtin_amdgcn_mfma_f32_16x16x32_f16(af, bhf[ni], acc[mi][ni], 0, 0, 0);
                acc[mi][ni] = __builtin_amdgcn_mfma_f32_16x16x32_f16(af, blf[ni], acc[mi][ni], 0, 0, 0);
            }
        }
    }

    // epilogue: store hh(f16) + fused alpha2
    int cn[3];
    float sa[3], da[3];
#pragma unroll
    for (int ni = 0; ni < 3; ni++) {
        cn[ni] = ni * 16 + lr;
        sa[ni] = (cn[ni] < NCLS) ? attS[cn[ni]] : 0.f;
        da[ni] = (cn[ni] < NCLS) ? attD[cn[ni]] : 0.f;
    }
#pragma unroll
    for (int mi = 0; mi < 2; mi++) {
#pragma unroll
        for (int r = 0; r < 4; r++) {
            int gr = row0 + R0 + mi * 16 + lg * 4 + r;
            float v0 = acc[mi][0][r], v1 = acc[mi][1][r], v2 = acc[mi][2][r];
            float ps = v0 * sa[0] + v1 * sa[1] + v2 * sa[2];
            float pd = v0 * da[0] + v1 * da[1] + v2 * da[2];
#pragma unroll
            for (int m = 1; m <= 8; m <<= 1) {
                ps += __shfl_xor(ps, m);
                pd += __shfl_xor(pd, m);
            }
            if (gr < NN) {
                if (lr == 0) { as2[gr] = ps; ad2[gr] = pd; }
                ushort_t* hp = hh + (size_t)gr * NCLS;
                if (cn[0] < NCLS) hp[cn[0]] = f2h(v0);
                if (cn[1] < NCLS) hp[cn[1]] = f2h(v1);
                if (cn[2] < NCLS) hp[cn[2]] = f2h(v2);
            }
        }
    }
}

// ----------------- softmax stats pass, layer 2 -----------------------------
__global__ __launch_bounds__(256) void k_soft2(const int* __restrict__ csr_src,
                                               const int* __restrict__ offset,
                                               const int* __restrict__ deg,
                                               const float* __restrict__ as2,
                                               const float* __restrict__ ad2,
                                               float* __restrict__ m2,
                                               float* __restrict__ di2) {
    int wave = (blockIdx.x * blockDim.x + threadIdx.x) >> 6;
    int lane = threadIdx.x & 63;
    if (wave >= NN) return;
    int d = wave;
    float ad = ad2[d];
    int beg = offset[d], cnt = deg[d];
    float m = -1e30f, s = 0.f;
    for (int j = lane; j < cnt; j += 64) {
        int src = csr_src[beg + j];
        float e = as2[src] + ad;
        e = (e > 0.f) ? e : SLOPE * e;
        float mn = fmaxf(m, e);
        s = s * __expf(m - mn) + __expf(e - mn);
        m = mn;
    }
#pragma unroll
    for (int mask = 1; mask <= 32; mask <<= 1) {
        float mo = __shfl_xor(m, mask);
        float so = __shfl_xor(s, mask);
        float mn = fmaxf(m, mo);
        s = s * __expf(m - mn) + so * __expf(mo - mn);
        m = mn;
    }
    if (lane == 0) {
        m2[d] = m;
        di2[d] = 1.f / (s + 1e-16f);
    }
}

// ----------------- aggregate pass, layer 2 (f16 gather) --------------------
__global__ __launch_bounds__(256) void k_agg2(const int* __restrict__ csr_src,
                                              const int* __restrict__ offset,
                                              const int* __restrict__ deg,
                                              const ushort_t* __restrict__ hh,
                                              const float* __restrict__ as2,
                                              const float* __restrict__ ad2,
                                              const float* __restrict__ m2,
                                              const float* __restrict__ di2,
                                              const float* __restrict__ bias2,
                                              float* __restrict__ out) {
    int wave = (blockIdx.x * blockDim.x + threadIdx.x) >> 6;
    int lane = threadIdx.x & 63;
    if (wave >= NN) return;
    int d = wave;
    float ad = ad2[d];
    float m = m2[d];
    float dinv = di2[d];
    int beg = offset[d], cnt = deg[d];
    float acc = 0.f;
#pragma unroll 4
    for (int j = 0; j < cnt; j++) {
        int s = csr_src[beg + j];
        float e = as2[s] + ad;
        e = (e > 0.f) ? e : SLOPE * e;
        float p = __expf(e - m);
        float hv = (lane < NCLS) ? (float)__builtin_bit_cast(_Float16, hh[(size_t)s * NCLS + lane]) : 0.f;
        acc += p * hv;
    }
    if (lane < NCLS) {
        out[(size_t)d * NCLS + lane] = acc * dinv + bias2[lane];
    }
}

extern "C" void kernel_launch(void* const* d_in, const int* in_sizes, int n_in,
                              void* d_out, int out_size, void* d_ws, size_t ws_size,
                              hipStream_t stream) {
    const float* x      = (const float*)d_in[0];
    const int* ei       = (const int*)d_in[1];   // int64 in ref -> int32 on device
    const float* W1     = (const float*)d_in[2];
    const float* att_s1 = (const float*)d_in[3];
    const float* att_d1 = (const float*)d_in[4];
    const float* bias1  = (const float*)d_in[5];
    const float* W2     = (const float*)d_in[6];
    const float* att_s2 = (const float*)d_in[7];
    const float* att_d2 = (const float*)d_in[8];
    const float* bias2  = (const float*)d_in[9];
    float* out = (float*)d_out;

    char* ws = (char*)d_ws;
    size_t off = 0;
    auto alloc = [&](size_t bytes) -> void* {
        void* p = ws + off;
        off = (off + bytes + 255) & ~(size_t)255;
        return p;
    };
    ushort_t* h1h = (ushort_t*)alloc((size_t)NN * 256 * 2);
    ushort_t* h2h = (ushort_t*)alloc((size_t)NN * 256 * 2);
    ushort_t* hh  = (ushort_t*)alloc((size_t)NN * NCLS * 2);
    float* as1  = (float*)alloc((size_t)NN * 8 * 4);
    float* ad1  = (float*)alloc((size_t)NN * 8 * 4);
    float* m1   = (float*)alloc((size_t)NN * 8 * 4);
    float* di1  = (float*)alloc((size_t)NN * 8 * 4);
    float* as2  = (float*)alloc((size_t)NN * 4);
    float* ad2  = (float*)alloc((size_t)NN * 4);
    float* m2   = (float*)alloc((size_t)NN * 4);
    float* di2  = (float*)alloc((size_t)NN * 4);
    int* deg    = (int*)alloc((size_t)NN * 4);
    int* offs   = (int*)alloc((size_t)(NN + 1) * 4);
    int* cursor = (int*)alloc((size_t)NN * 4);
    int* csr    = (int*)alloc((size_t)ETOT * 4);
    int* bsum   = (int*)alloc(4096);
    ushort_t* W1ht = (ushort_t*)alloc((size_t)256 * 256 * 2);
    ushort_t* W1lt = (ushort_t*)alloc((size_t)256 * 256 * 2);
    ushort_t* W2ht = (ushort_t*)alloc((size_t)48 * 256 * 2);
    ushort_t* W2lt = (ushort_t*)alloc((size_t)48 * 256 * 2);

    // CSR build
    k_deg_init<<<(NN + 255) / 256, 256, 0, stream>>>(deg);
    k_hist<<<(NE + 255) / 256, 256, 0, stream>>>(ei, deg);
    k_blocksum<<<NBLK, SCAN_B, 0, stream>>>(deg, bsum);
    k_scan_bsums<<<1, 1024, 0, stream>>>(bsum, NBLK);
    k_offsets<<<NBLK, SCAN_B, 0, stream>>>(deg, bsum, offs, cursor, csr);
    k_scatter<<<(NE + 255) / 256, 256, 0, stream>>>(ei, cursor, csr);

    // Layer 1
    k_splitW<<<256, 256, 0, stream>>>(W1, W1ht, W1lt);
    k_gemm1<<<((NN + 127) / 128) * 2, 256, 0, stream>>>(x, W1ht, W1lt, att_s1, att_d1, h1h, as1, ad1);
    k_soft1<<<(NN + 3) / 4, 256, 0, stream>>>(csr, offs, deg, as1, ad1, m1, di1);
    k_agg1<<<(NN + 3) / 4, 256, 0, stream>>>(csr, offs, deg, h1h, as1, ad1, m1, di1, bias1, h2h);

    // Layer 2
    k_splitW2<<<48, 256, 0, stream>>>(W2, W2ht, W2lt);
    k_gemm2<<<(NN + 127) / 128, 256, 0, stream>>>(h2h, W2ht, W2lt, att_s2, att_d2, hh, as2, ad2);
    k_soft2<<<(NN + 3) / 4, 256, 0, stream>>>(csr, offs, deg, as2, ad2, m2, di2);
    k_agg2<<<(NN + 3) / 4, 256, 0, stream>>>(csr, offs, deg, hh, as2, ad2, m2, di2, bias2, out);
}

// Round 7
// 588.251 us; speedup vs baseline: 1.1210x; 1.1210x over previous
//
#include <hip/hip_runtime.h>
#include <math.h>

#define NN 100000
#define NE 1600000
#define ETOT (NE + NN)
#define HEADS 8
#define NCLS 40
#define SLOPE 0.2f

#define SCAN_B 512
#define NBLK ((NN + SCAN_B - 1) / SCAN_B)   // 196

typedef unsigned short ushort_t;
typedef __attribute__((ext_vector_type(8))) short short8;
typedef __attribute__((ext_vector_type(8))) _Float16 half8;
typedef __attribute__((ext_vector_type(4))) float f32x4;

static __device__ __forceinline__ ushort_t f2bf(float f) {
    unsigned u = __float_as_uint(f);
    unsigned r = (u + 0x7FFFu + ((u >> 16) & 1u)) >> 16;   // RNE
    return (ushort_t)r;
}
static __device__ __forceinline__ float bf2f(ushort_t b) {
    return __uint_as_float(((unsigned)b) << 16);
}
static __device__ __forceinline__ ushort_t f2h(float f) {
    _Float16 h = (_Float16)f;
    return __builtin_bit_cast(ushort_t, h);
}
static __device__ __forceinline__ float h2f(ushort_t u) {
    return (float)__builtin_bit_cast(_Float16, u);
}

// ----------------- CSR build -----------------
__global__ void k_deg_init(int* __restrict__ deg) {
    int i = blockIdx.x * blockDim.x + threadIdx.x;
    if (i < NN) deg[i] = 1;  // self loop
}

__global__ void k_hist(const int* __restrict__ ei, int* __restrict__ deg) {
    int e = blockIdx.x * blockDim.x + threadIdx.x;
    if (e < NE) {
        unsigned d = (unsigned)ei[NE + e];
        if (d < NN) atomicAdd(&deg[d], 1);
    }
}

__global__ void k_blocksum(const int* __restrict__ deg, int* __restrict__ bsum) {
    __shared__ int sh[SCAN_B];
    int b = blockIdx.x;
    int i = b * SCAN_B + threadIdx.x;
    sh[threadIdx.x] = (i < NN) ? deg[i] : 0;
    __syncthreads();
    for (int s = SCAN_B / 2; s > 0; s >>= 1) {
        if (threadIdx.x < s) sh[threadIdx.x] += sh[threadIdx.x + s];
        __syncthreads();
    }
    if (threadIdx.x == 0) bsum[b] = sh[0];
}

__global__ void k_scan_bsums(int* __restrict__ bsum, int nblk) {
    __shared__ int sh[1024];
    int t = threadIdx.x;
    int v = (t < nblk) ? bsum[t] : 0;
    sh[t] = v;
    __syncthreads();
    for (int o = 1; o < 1024; o <<= 1) {
        int add = (t >= o) ? sh[t - o] : 0;
        __syncthreads();
        sh[t] += add;
        __syncthreads();
    }
    if (t < nblk) bsum[t] = sh[t] - v;  // exclusive
}

__global__ void k_offsets(const int* __restrict__ deg, const int* __restrict__ bsum,
                          int* __restrict__ offset, int* __restrict__ cursor,
                          int* __restrict__ csr_src) {
    __shared__ int sh[SCAN_B];
    int b = blockIdx.x, t = threadIdx.x;
    int i = b * SCAN_B + t;
    int v = (i < NN) ? deg[i] : 0;
    sh[t] = v;
    __syncthreads();
    for (int o = 1; o < SCAN_B; o <<= 1) {
        int add = (t >= o) ? sh[t - o] : 0;
        __syncthreads();
        sh[t] += add;
        __syncthreads();
    }
    if (i < NN) {
        int excl = sh[t] - v + bsum[b];
        offset[i] = excl;
        cursor[i] = excl + 1;
        csr_src[excl] = i;  // pre-place self loop
    }
}

__global__ void k_scatter(const int* __restrict__ ei, int* __restrict__ cursor,
                          int* __restrict__ csr_src) {
    int e = blockIdx.x * blockDim.x + threadIdx.x;
    if (e < NE) {
        unsigned d = (unsigned)ei[NE + e];
        unsigned s = (unsigned)ei[e];
        if (d < NN && s < NN) {
            int pos = atomicAdd(&cursor[d], 1);
            csr_src[pos] = (int)s;
        }
    }
}

// ----------------- split W1 into bf16 hi/lo, transposed [n][k] -------------
__global__ void k_splitW(const float* __restrict__ W, ushort_t* __restrict__ Wht,
                         ushort_t* __restrict__ Wlt) {
    int k = blockIdx.x;          // 256 blocks
    int n = threadIdx.x;         // 256 threads
    float v = W[k * 256 + n];
    ushort_t hi = f2bf(v);
    ushort_t lo = f2bf(v - bf2f(hi));
    Wht[n * 256 + k] = hi;
    Wlt[n * 256 + k] = lo;
}

// ----------------- split W2 [256][40] -> padded transposed [48][256] f16 ---
__global__ void k_splitW2(const float* __restrict__ W, ushort_t* __restrict__ Wht,
                          ushort_t* __restrict__ Wlt) {
    int n = blockIdx.x;          // 48 blocks
    int k = threadIdx.x;         // 256 threads
    float v = (n < NCLS) ? W[k * NCLS + n] : 0.f;
    ushort_t hi = f2h(v);
    ushort_t lo = f2h(v - h2f(hi));
    Wht[n * 256 + k] = hi;
    Wlt[n * 256 + k] = lo;
}

// ----------------- GEMM1 (MFMA split-bf16): h1h(f16) = x @ W1; fused alphas
#define LSTR 40   // ushorts per LDS row
__global__ __launch_bounds__(256) void k_gemm1(const float* __restrict__ A,
                                               const ushort_t* __restrict__ Bht,
                                               const ushort_t* __restrict__ Blt,
                                               const float* __restrict__ attS,
                                               const float* __restrict__ attD,
                                               ushort_t* __restrict__ h1h,
                                               float* __restrict__ as1,
                                               float* __restrict__ ad1) {
    __shared__ ushort_t Ah[128 * LSTR];
    __shared__ ushort_t Al[128 * LSTR];
    __shared__ ushort_t Bh[128 * LSTR];
    __shared__ ushort_t Bl[128 * LSTR];

    int bx = blockIdx.x & 1;
    int by = blockIdx.x >> 1;
    int row0 = by * 128, col0 = bx * 128;
    int t = threadIdx.x;
    int w = t >> 6, lane = t & 63;
    int lr = lane & 15, lg = lane >> 4;
    int R0 = (w >> 1) * 64, C0 = (w & 1) * 64;

    int ar = t >> 1, ah = t & 1;          // A: row, k-half(16 f32)
    int gr_a = row0 + ar;

    f32x4 acc[4][4];
#pragma unroll
    for (int i = 0; i < 4; i++)
#pragma unroll
        for (int j = 0; j < 4; j++) acc[i][j] = (f32x4){0.f, 0.f, 0.f, 0.f};

    for (int it = 0; it < 8; it++) {
        int k0 = it * 32;
        __syncthreads();
        // ---- stage A (convert f32 -> bf16 hi/lo) ----
        {
            float f[16];
            if (gr_a < NN) {
                const float* ap = A + (size_t)gr_a * 256 + k0 + ah * 16;
#pragma unroll
                for (int i = 0; i < 4; i++) {
                    float4 v = *reinterpret_cast<const float4*>(ap + i * 4);
                    f[i * 4 + 0] = v.x; f[i * 4 + 1] = v.y; f[i * 4 + 2] = v.z; f[i * 4 + 3] = v.w;
                }
            } else {
#pragma unroll
                for (int i = 0; i < 16; i++) f[i] = 0.f;
            }
            unsigned hw[8], lw[8];
#pragma unroll
            for (int i = 0; i < 8; i++) {
                ushort_t h0 = f2bf(f[2 * i]), h1v = f2bf(f[2 * i + 1]);
                ushort_t l0 = f2bf(f[2 * i] - bf2f(h0)), l1 = f2bf(f[2 * i + 1] - bf2f(h1v));
                hw[i] = (unsigned)h0 | ((unsigned)h1v << 16);
                lw[i] = (unsigned)l0 | ((unsigned)l1 << 16);
            }
            uint4* dsth = reinterpret_cast<uint4*>(&Ah[ar * LSTR + ah * 16]);
            dsth[0] = make_uint4(hw[0], hw[1], hw[2], hw[3]);
            dsth[1] = make_uint4(hw[4], hw[5], hw[6], hw[7]);
            uint4* dstl = reinterpret_cast<uint4*>(&Al[ar * LSTR + ah * 16]);
            dstl[0] = make_uint4(lw[0], lw[1], lw[2], lw[3]);
            dstl[1] = make_uint4(lw[4], lw[5], lw[6], lw[7]);
        }
        // ---- stage B (pre-split, pre-transposed [n][k]) ----
        {
            int bn = t >> 1, bh2 = t & 1;
            const uint4* sh = reinterpret_cast<const uint4*>(Bht + (size_t)(col0 + bn) * 256 + k0 + bh2 * 16);
            const uint4* sl = reinterpret_cast<const uint4*>(Blt + (size_t)(col0 + bn) * 256 + k0 + bh2 * 16);
            uint4* dh = reinterpret_cast<uint4*>(&Bh[bn * LSTR + bh2 * 16]);
            uint4* dl = reinterpret_cast<uint4*>(&Bl[bn * LSTR + bh2 * 16]);
            dh[0] = sh[0]; dh[1] = sh[1];
            dl[0] = sl[0]; dl[1] = sl[1];
        }
        __syncthreads();
        // ---- fragments + MFMA ----
        short8 bhf[4], blf[4];
#pragma unroll
        for (int ni = 0; ni < 4; ni++) {
            int c = C0 + ni * 16 + lr;
            bhf[ni] = *reinterpret_cast<const short8*>(&Bh[c * LSTR + lg * 8]);
            blf[ni] = *reinterpret_cast<const short8*>(&Bl[c * LSTR + lg * 8]);
        }
#pragma unroll
        for (int mi = 0; mi < 4; mi++) {
            int r = R0 + mi * 16 + lr;
            short8 ahf = *reinterpret_cast<const short8*>(&Ah[r * LSTR + lg * 8]);
            short8 alf = *reinterpret_cast<const short8*>(&Al[r * LSTR + lg * 8]);
#pragma unroll
            for (int ni = 0; ni < 4; ni++) {
                acc[mi][ni] = __builtin_amdgcn_mfma_f32_16x16x32_bf16(ahf, bhf[ni], acc[mi][ni], 0, 0, 0);
                acc[mi][ni] = __builtin_amdgcn_mfma_f32_16x16x32_bf16(alf, bhf[ni], acc[mi][ni], 0, 0, 0);
                acc[mi][ni] = __builtin_amdgcn_mfma_f32_16x16x32_bf16(ahf, blf[ni], acc[mi][ni], 0, 0, 0);
            }
        }
    }

    // ---- epilogue: f16 store + fused alpha dots ----
    int cn[4];
    float sa[4], da[4];
#pragma unroll
    for (int ni = 0; ni < 4; ni++) {
        cn[ni] = col0 + C0 + ni * 16 + lr;
        sa[ni] = attS[cn[ni]];
        da[ni] = attD[cn[ni]];
    }
    int head0 = (col0 + C0) >> 5;
#pragma unroll
    for (int mi = 0; mi < 4; mi++) {
#pragma unroll
        for (int r = 0; r < 4; r++) {
            int gr = row0 + R0 + mi * 16 + lg * 4 + r;
            float v0 = acc[mi][0][r], v1 = acc[mi][1][r];
            float v2 = acc[mi][2][r], v3 = acc[mi][3][r];
            float ps0 = v0 * sa[0] + v1 * sa[1];
            float pd0 = v0 * da[0] + v1 * da[1];
            float ps1 = v2 * sa[2] + v3 * sa[3];
            float pd1 = v2 * da[2] + v3 * da[3];
#pragma unroll
            for (int m = 1; m <= 8; m <<= 1) {
                ps0 += __shfl_xor(ps0, m);
                pd0 += __shfl_xor(pd0, m);
                ps1 += __shfl_xor(ps1, m);
                pd1 += __shfl_xor(pd1, m);
            }
            if (gr < NN) {
                if (lr == 0) {
                    as1[gr * 8 + head0] = ps0;
                    ad1[gr * 8 + head0] = pd0;
                    as1[gr * 8 + head0 + 1] = ps1;
                    ad1[gr * 8 + head0 + 1] = pd1;
                }
                ushort_t* hp = h1h + (size_t)gr * 256;
                hp[cn[0]] = f2h(v0);
                hp[cn[1]] = f2h(v1);
                hp[cn[2]] = f2h(v2);
                hp[cn[3]] = f2h(v3);
            }
        }
    }
}

// ------- softmax stats + weight write, layer 1: one wave/node --------------
// lane = sub(edge stride, bits 3..5) x head(bits 0..2)
__global__ __launch_bounds__(256) void k_soft1(const int* __restrict__ csr_src,
                                               const int* __restrict__ offset,
                                               const int* __restrict__ deg,
                                               const float* __restrict__ as1,
                                               const float* __restrict__ ad1,
                                               float* __restrict__ w1) {
    int wave = (blockIdx.x * blockDim.x + threadIdx.x) >> 6;
    int lane = threadIdx.x & 63;
    if (wave >= NN) return;
    int d = wave;
    int sub = lane >> 3, h = lane & 7;
    float ad = ad1[d * 8 + h];
    int beg = offset[d], cnt = deg[d];
    float m = -1e30f, s = 0.f;
    for (int j = sub; j < cnt; j += 8) {
        int src = csr_src[beg + j];
        float e = as1[src * 8 + h] + ad;
        e = (e > 0.f) ? e : SLOPE * e;
        float mn = fmaxf(m, e);
        s = s * __expf(m - mn) + __expf(e - mn);
        m = mn;
    }
#pragma unroll
    for (int mask = 8; mask <= 32; mask <<= 1) {
        float mo = __shfl_xor(m, mask);
        float so = __shfl_xor(s, mask);
        float mn = fmaxf(m, mo);
        s = s * __expf(m - mn) + so * __expf(mo - mn);
        m = mn;
    }
    float di = 1.f / (s + 1e-16f);
    // phase 2: write normalized weights, CSR order, coalesced
    for (int j = sub; j < cnt; j += 8) {
        int src = csr_src[beg + j];
        float e = as1[src * 8 + h] + ad;
        e = (e > 0.f) ? e : SLOPE * e;
        w1[(size_t)(beg + j) * 8 + h] = __expf(e - m) * di;
    }
}

// ----------------- aggregate pass, layer 1: pure w*gather ------------------
__global__ __launch_bounds__(256) void k_agg1(const int* __restrict__ csr_src,
                                              const int* __restrict__ offset,
                                              const int* __restrict__ deg,
                                              const ushort_t* __restrict__ h1h,
                                              const float* __restrict__ w1,
                                              const float* __restrict__ bias1,
                                              ushort_t* __restrict__ h2h) {
    int wave = (blockIdx.x * blockDim.x + threadIdx.x) >> 6;
    int lane = threadIdx.x & 63;
    if (wave >= NN) return;
    int d = wave;
    int h = lane >> 3;
    int f0 = lane * 4;
    int beg = offset[d], cnt = deg[d];
    float ax = 0.f, ay = 0.f, az = 0.f, aw = 0.f;
#pragma unroll 4
    for (int j = 0; j < cnt; j++) {
        int s = csr_src[beg + j];
        float w = w1[(size_t)(beg + j) * 8 + h];
        ushort4 hv = *reinterpret_cast<const ushort4*>(h1h + (size_t)s * 256 + f0);
        ax += w * (float)__builtin_bit_cast(_Float16, hv.x);
        ay += w * (float)__builtin_bit_cast(_Float16, hv.y);
        az += w * (float)__builtin_bit_cast(_Float16, hv.z);
        aw += w * (float)__builtin_bit_cast(_Float16, hv.w);
    }
    float4 b = *reinterpret_cast<const float4*>(bias1 + f0);
    float vx = ax + b.x;
    float vy = ay + b.y;
    float vz = az + b.z;
    float vw = aw + b.w;
    vx = (vx > 0.f) ? vx : expm1f(vx);
    vy = (vy > 0.f) ? vy : expm1f(vy);
    vz = (vz > 0.f) ? vz : expm1f(vz);
    vw = (vw > 0.f) ? vw : expm1f(vw);
    ushort4 o;
    o.x = f2h(vx); o.y = f2h(vy); o.z = f2h(vz); o.w = f2h(vw);
    *reinterpret_cast<ushort4*>(h2h + (size_t)d * 256 + f0) = o;
}

// ----------------- GEMM2 (MFMA f16): hh(f16) = h2h @ W2; fused alpha2 ------
__global__ __launch_bounds__(256) void k_gemm2(const ushort_t* __restrict__ A,
                                               const ushort_t* __restrict__ Bht,
                                               const ushort_t* __restrict__ Blt,
                                               const float* __restrict__ attS,
                                               const float* __restrict__ attD,
                                               ushort_t* __restrict__ hh,
                                               float* __restrict__ as2,
                                               float* __restrict__ ad2) {
    __shared__ ushort_t Ash[128 * LSTR];
    __shared__ ushort_t Bh[48 * LSTR];
    __shared__ ushort_t Bl[48 * LSTR];
    int row0 = blockIdx.x * 128;
    int t = threadIdx.x;
    int w = t >> 6, lane = t & 63;
    int lr = lane & 15, lg = lane >> 4;
    int R0 = w * 32;

    f32x4 acc[2][3];
#pragma unroll
    for (int i = 0; i < 2; i++)
#pragma unroll
        for (int j = 0; j < 3; j++) acc[i][j] = (f32x4){0.f, 0.f, 0.f, 0.f};

    for (int it = 0; it < 8; it++) {
        int k0 = it * 32;
        __syncthreads();
        // stage A: 128 rows x 32 ushorts = 512 uint4 chunks
#pragma unroll
        for (int i = 0; i < 2; i++) {
            int chunk = t + i * 256;
            int r = chunk >> 2, part = chunk & 3;
            int gr = row0 + r;
            uint4 v = make_uint4(0u, 0u, 0u, 0u);
            if (gr < NN) v = *reinterpret_cast<const uint4*>(A + (size_t)gr * 256 + k0 + part * 8);
            *reinterpret_cast<uint4*>(&Ash[r * LSTR + part * 8]) = v;
        }
        // stage B: 48 rows x 32 ushorts = 192 uint4 chunks
        if (t < 192) {
            int bn = t >> 2, part = t & 3;
            *reinterpret_cast<uint4*>(&Bh[bn * LSTR + part * 8]) =
                *reinterpret_cast<const uint4*>(Bht + (size_t)bn * 256 + k0 + part * 8);
            *reinterpret_cast<uint4*>(&Bl[bn * LSTR + part * 8]) =
                *reinterpret_cast<const uint4*>(Blt + (size_t)bn * 256 + k0 + part * 8);
        }
        __syncthreads();
        half8 bhf[3], blf[3];
#pragma unroll
        for (int ni = 0; ni < 3; ni++) {
            int c = ni * 16 + lr;
            bhf[ni] = *reinterpret_cast<const half8*>(&Bh[c * LSTR + lg * 8]);
            blf[ni] = *reinterpret_cast<const half8*>(&Bl[c * LSTR + lg * 8]);
        }
#pragma unroll
        for (int mi = 0; mi < 2; mi++) {
            int r = R0 + mi * 16 + lr;
            half8 af = *reinterpret_cast<const half8*>(&Ash[r * LSTR + lg * 8]);
#pragma unroll
            for (int ni = 0; ni < 3; ni++) {
                acc[mi][ni] = __builtin_amdgcn_mfma_f32_16x16x32_f16(af, bhf[ni], acc[mi][ni], 0, 0, 0);
                acc[mi][ni] = __builtin_amdgcn_mfma_f32_16x16x32_f16(af, blf[ni], acc[mi][ni], 0, 0, 0);
            }
        }
    }

    // epilogue: store hh(f16) + fused alpha2
    int cn[3];
    float sa[3], da[3];
#pragma unroll
    for (int ni = 0; ni < 3; ni++) {
        cn[ni] = ni * 16 + lr;
        sa[ni] = (cn[ni] < NCLS) ? attS[cn[ni]] : 0.f;
        da[ni] = (cn[ni] < NCLS) ? attD[cn[ni]] : 0.f;
    }
#pragma unroll
    for (int mi = 0; mi < 2; mi++) {
#pragma unroll
        for (int r = 0; r < 4; r++) {
            int gr = row0 + R0 + mi * 16 + lg * 4 + r;
            float v0 = acc[mi][0][r], v1 = acc[mi][1][r], v2 = acc[mi][2][r];
            float ps = v0 * sa[0] + v1 * sa[1] + v2 * sa[2];
            float pd = v0 * da[0] + v1 * da[1] + v2 * da[2];
#pragma unroll
            for (int m = 1; m <= 8; m <<= 1) {
                ps += __shfl_xor(ps, m);
                pd += __shfl_xor(pd, m);
            }
            if (gr < NN) {
                if (lr == 0) { as2[gr] = ps; ad2[gr] = pd; }
                ushort_t* hp = hh + (size_t)gr * NCLS;
                if (cn[0] < NCLS) hp[cn[0]] = f2h(v0);
                if (cn[1] < NCLS) hp[cn[1]] = f2h(v1);
                if (cn[2] < NCLS) hp[cn[2]] = f2h(v2);
            }
        }
    }
}

// ------- softmax stats + weight write, layer 2: one wave/node --------------
__global__ __launch_bounds__(256) void k_soft2(const int* __restrict__ csr_src,
                                               const int* __restrict__ offset,
                                               const int* __restrict__ deg,
                                               const float* __restrict__ as2,
                                               const float* __restrict__ ad2,
                                               float* __restrict__ w2) {
    int wave = (blockIdx.x * blockDim.x + threadIdx.x) >> 6;
    int lane = threadIdx.x & 63;
    if (wave >= NN) return;
    int d = wave;
    float ad = ad2[d];
    int beg = offset[d], cnt = deg[d];
    float m = -1e30f, s = 0.f;
    for (int j = lane; j < cnt; j += 64) {
        int src = csr_src[beg + j];
        float e = as2[src] + ad;
        e = (e > 0.f) ? e : SLOPE * e;
        float mn = fmaxf(m, e);
        s = s * __expf(m - mn) + __expf(e - mn);
        m = mn;
    }
#pragma unroll
    for (int mask = 1; mask <= 32; mask <<= 1) {
        float mo = __shfl_xor(m, mask);
        float so = __shfl_xor(s, mask);
        float mn = fmaxf(m, mo);
        s = s * __expf(m - mn) + so * __expf(mo - mn);
        m = mn;
    }
    float di = 1.f / (s + 1e-16f);
    for (int j = lane; j < cnt; j += 64) {
        int src = csr_src[beg + j];
        float e = as2[src] + ad;
        e = (e > 0.f) ? e : SLOPE * e;
        w2[beg + j] = __expf(e - m) * di;
    }
}

// ------- aggregate pass, layer 2: 3 edges in flight, 20 lanes each ---------
__global__ __launch_bounds__(256) void k_agg2(const int* __restrict__ csr_src,
                                              const int* __restrict__ offset,
                                              const int* __restrict__ deg,
                                              const ushort_t* __restrict__ hh,
                                              const float* __restrict__ w2,
                                              const float* __restrict__ bias2,
                                              float* __restrict__ out) {
    int wave = (blockIdx.x * blockDim.x + threadIdx.x) >> 6;
    int lane = threadIdx.x & 63;
    if (wave >= NN) return;
    int d = wave;
    int es = lane / 20;       // edge slot 0..2 (3 = idle)
    int ch = lane % 20;       // uint chunk -> classes 2ch, 2ch+1
    int beg = offset[d], cnt = deg[d];
    float a0 = 0.f, a1 = 0.f;
    for (int j0 = 0; j0 < cnt; j0 += 3) {
        int j = j0 + es;
        if (es < 3 && j < cnt) {
            int s = csr_src[beg + j];
            float w = w2[beg + j];
            unsigned v = *reinterpret_cast<const unsigned*>(hh + (size_t)s * NCLS + ch * 2);
            a0 += w * (float)__builtin_bit_cast(_Float16, (ushort_t)(v & 0xFFFFu));
            a1 += w * (float)__builtin_bit_cast(_Float16, (ushort_t)(v >> 16));
        }
    }
    float t0 = __shfl(a0, lane + 20);
    float t1 = __shfl(a0, lane + 40);
    float u0 = __shfl(a1, lane + 20);
    float u1 = __shfl(a1, lane + 40);
    if (lane < 20) {
        float2 o;
        o.x = a0 + t0 + t1 + bias2[ch * 2];
        o.y = a1 + u0 + u1 + bias2[ch * 2 + 1];
        *reinterpret_cast<float2*>(out + (size_t)d * NCLS + ch * 2) = o;
    }
}

extern "C" void kernel_launch(void* const* d_in, const int* in_sizes, int n_in,
                              void* d_out, int out_size, void* d_ws, size_t ws_size,
                              hipStream_t stream) {
    const float* x      = (const float*)d_in[0];
    const int* ei       = (const int*)d_in[1];   // int64 in ref -> int32 on device
    const float* W1     = (const float*)d_in[2];
    const float* att_s1 = (const float*)d_in[3];
    const float* att_d1 = (const float*)d_in[4];
    const float* bias1  = (const float*)d_in[5];
    const float* W2     = (const float*)d_in[6];
    const float* att_s2 = (const float*)d_in[7];
    const float* att_d2 = (const float*)d_in[8];
    const float* bias2  = (const float*)d_in[9];
    float* out = (float*)d_out;

    char* ws = (char*)d_ws;
    size_t off = 0;
    auto alloc = [&](size_t bytes) -> void* {
        void* p = ws + off;
        off = (off + bytes + 255) & ~(size_t)255;
        return p;
    };
    ushort_t* h1h = (ushort_t*)alloc((size_t)NN * 256 * 2);
    ushort_t* h2h = (ushort_t*)alloc((size_t)NN * 256 * 2);
    ushort_t* hh  = (ushort_t*)alloc((size_t)NN * NCLS * 2);
    float* as1  = (float*)alloc((size_t)NN * 8 * 4);
    float* ad1  = (float*)alloc((size_t)NN * 8 * 4);
    float* as2  = (float*)alloc((size_t)NN * 4);
    float* ad2  = (float*)alloc((size_t)NN * 4);
    float* w1   = (float*)alloc((size_t)ETOT * 8 * 4);
    float* w2   = (float*)alloc((size_t)ETOT * 4);
    int* deg    = (int*)alloc((size_t)NN * 4);
    int* offs   = (int*)alloc((size_t)(NN + 1) * 4);
    int* cursor = (int*)alloc((size_t)NN * 4);
    int* csr    = (int*)alloc((size_t)ETOT * 4);
    int* bsum   = (int*)alloc(4096);
    ushort_t* W1ht = (ushort_t*)alloc((size_t)256 * 256 * 2);
    ushort_t* W1lt = (ushort_t*)alloc((size_t)256 * 256 * 2);
    ushort_t* W2ht = (ushort_t*)alloc((size_t)48 * 256 * 2);
    ushort_t* W2lt = (ushort_t*)alloc((size_t)48 * 256 * 2);

    // CSR build
    k_deg_init<<<(NN + 255) / 256, 256, 0, stream>>>(deg);
    k_hist<<<(NE + 255) / 256, 256, 0, stream>>>(ei, deg);
    k_blocksum<<<NBLK, SCAN_B, 0, stream>>>(deg, bsum);
    k_scan_bsums<<<1, 1024, 0, stream>>>(bsum, NBLK);
    k_offsets<<<NBLK, SCAN_B, 0, stream>>>(deg, bsum, offs, cursor, csr);
    k_scatter<<<(NE + 255) / 256, 256, 0, stream>>>(ei, cursor, csr);

    // Layer 1
    k_splitW<<<256, 256, 0, stream>>>(W1, W1ht, W1lt);
    k_gemm1<<<((NN + 127) / 128) * 2, 256, 0, stream>>>(x, W1ht, W1lt, att_s1, att_d1, h1h, as1, ad1);
    k_soft1<<<(NN + 3) / 4, 256, 0, stream>>>(csr, offs, deg, as1, ad1, w1);
    k_agg1<<<(NN + 3) / 4, 256, 0, stream>>>(csr, offs, deg, h1h, w1, bias1, h2h);

    // Layer 2
    k_splitW2<<<48, 256, 0, stream>>>(W2, W2ht, W2lt);
    k_gemm2<<<(NN + 127) / 128, 256, 0, stream>>>(h2h, W2ht, W2lt, att_s2, att_d2, hh, as2, ad2);
    k_soft2<<<(NN + 3) / 4, 256, 0, stream>>>(csr, offs, deg, as2, ad2, w2);
    k_agg2<<<(NN + 3) / 4, 256, 0, stream>>>(csr, offs, deg, hh, w2, bias2, out);
}

// Round 8
// 537.981 us; speedup vs baseline: 1.2257x; 1.0934x over previous
//
#include <hip/hip_runtime.h>
#include <math.h>

#define NN 100000
#define NE 1600000
#define ETOT (NE + NN)
#define HEADS 8
#define NCLS 40
#define SLOPE 0.2f

#define SCAN_B 512
#define NBLK ((NN + SCAN_B - 1) / SCAN_B)   // 196
#define GB1 (((NN + 127) / 128) * 2)        // gemm1 blocks: 1564
#define SCB ((NE + 255) / 256)              // scatter blocks: 6250

typedef unsigned short ushort_t;
typedef __attribute__((ext_vector_type(8))) short short8;
typedef __attribute__((ext_vector_type(8))) _Float16 half8;
typedef __attribute__((ext_vector_type(4))) float f32x4;

static __device__ __forceinline__ ushort_t f2bf(float f) {
    unsigned u = __float_as_uint(f);
    unsigned r = (u + 0x7FFFu + ((u >> 16) & 1u)) >> 16;   // RNE
    return (ushort_t)r;
}
static __device__ __forceinline__ float bf2f(ushort_t b) {
    return __uint_as_float(((unsigned)b) << 16);
}
static __device__ __forceinline__ ushort_t f2h(float f) {
    _Float16 h = (_Float16)f;
    return __builtin_bit_cast(ushort_t, h);
}
static __device__ __forceinline__ float h2f(ushort_t u) {
    return (float)__builtin_bit_cast(_Float16, u);
}

// ----------------- CSR build -----------------
__global__ void k_deg_init(int* __restrict__ deg) {
    int i = blockIdx.x * blockDim.x + threadIdx.x;
    if (i < NN) deg[i] = 1;  // self loop
}

__global__ void k_hist(const int* __restrict__ ei, int* __restrict__ deg) {
    int e = blockIdx.x * blockDim.x + threadIdx.x;
    if (e < NE) {
        unsigned d = (unsigned)ei[NE + e];
        if (d < NN) atomicAdd(&deg[d], 1);
    }
}

__global__ void k_blocksum(const int* __restrict__ deg, int* __restrict__ bsum) {
    __shared__ int sh[SCAN_B];
    int b = blockIdx.x;
    int i = b * SCAN_B + threadIdx.x;
    sh[threadIdx.x] = (i < NN) ? deg[i] : 0;
    __syncthreads();
    for (int s = SCAN_B / 2; s > 0; s >>= 1) {
        if (threadIdx.x < s) sh[threadIdx.x] += sh[threadIdx.x + s];
        __syncthreads();
    }
    if (threadIdx.x == 0) bsum[b] = sh[0];
}

__global__ void k_scan_bsums(int* __restrict__ bsum, int nblk) {
    __shared__ int sh[1024];
    int t = threadIdx.x;
    int v = (t < nblk) ? bsum[t] : 0;
    sh[t] = v;
    __syncthreads();
    for (int o = 1; o < 1024; o <<= 1) {
        int add = (t >= o) ? sh[t - o] : 0;
        __syncthreads();
        sh[t] += add;
        __syncthreads();
    }
    if (t < nblk) bsum[t] = sh[t] - v;  // exclusive
}

__global__ void k_offsets(const int* __restrict__ deg, const int* __restrict__ bsum,
                          int* __restrict__ offset, int* __restrict__ cursor,
                          int* __restrict__ csr_src) {
    __shared__ int sh[SCAN_B];
    int b = blockIdx.x, t = threadIdx.x;
    int i = b * SCAN_B + t;
    int v = (i < NN) ? deg[i] : 0;
    sh[t] = v;
    __syncthreads();
    for (int o = 1; o < SCAN_B; o <<= 1) {
        int add = (t >= o) ? sh[t - o] : 0;
        __syncthreads();
        sh[t] += add;
        __syncthreads();
    }
    if (i < NN) {
        int excl = sh[t] - v + bsum[b];
        offset[i] = excl;
        cursor[i] = excl + 1;
        csr_src[excl] = i;  // pre-place self loop
    }
}

// ----------------- split W1 into bf16 hi/lo, transposed [n][k] -------------
__global__ void k_splitW(const float* __restrict__ W, ushort_t* __restrict__ Wht,
                         ushort_t* __restrict__ Wlt) {
    int k = blockIdx.x;          // 256 blocks
    int n = threadIdx.x;         // 256 threads
    float v = W[k * 256 + n];
    ushort_t hi = f2bf(v);
    ushort_t lo = f2bf(v - bf2f(hi));
    Wht[n * 256 + k] = hi;
    Wlt[n * 256 + k] = lo;
}

// ----------------- split W2 [256][40] -> padded transposed [48][256] f16 ---
__global__ void k_splitW2(const float* __restrict__ W, ushort_t* __restrict__ Wht,
                          ushort_t* __restrict__ Wlt) {
    int n = blockIdx.x;          // 48 blocks
    int k = threadIdx.x;         // 256 threads
    float v = (n < NCLS) ? W[k * NCLS + n] : 0.f;
    ushort_t hi = f2h(v);
    ushort_t lo = f2h(v - h2f(hi));
    Wht[n * 256 + k] = hi;
    Wlt[n * 256 + k] = lo;
}

// ----- FUSED: GEMM1 (blocks < GB1) + edge scatter (blocks >= GB1) ----------
// GEMM1 (MFMA split-bf16): h1h(f16) = x @ W1; fused alphas.
// Scatter: csr_src[atomic cursor[dst]++] = src  (independent of GEMM).
#define LSTR 40   // ushorts per LDS row
__global__ __launch_bounds__(256) void k_gemm1s(const float* __restrict__ A,
                                                const ushort_t* __restrict__ Bht,
                                                const ushort_t* __restrict__ Blt,
                                                const float* __restrict__ attS,
                                                const float* __restrict__ attD,
                                                ushort_t* __restrict__ h1h,
                                                float* __restrict__ as1,
                                                float* __restrict__ ad1,
                                                const int* __restrict__ ei,
                                                int* __restrict__ cursor,
                                                int* __restrict__ csr_src) {
    __shared__ ushort_t Ah[128 * LSTR];
    __shared__ ushort_t Al[128 * LSTR];
    __shared__ ushort_t Bh[128 * LSTR];
    __shared__ ushort_t Bl[128 * LSTR];

    if (blockIdx.x >= GB1) {
        // ---------------- scatter body ----------------
        int e = (blockIdx.x - GB1) * 256 + threadIdx.x;
        if (e < NE) {
            unsigned d = (unsigned)ei[NE + e];
            unsigned s = (unsigned)ei[e];
            if (d < NN && s < NN) {
                int pos = atomicAdd(&cursor[d], 1);
                csr_src[pos] = (int)s;
            }
        }
        return;
    }

    // ---------------- GEMM body ----------------
    int bx = blockIdx.x & 1;
    int by = blockIdx.x >> 1;
    int row0 = by * 128, col0 = bx * 128;
    int t = threadIdx.x;
    int w = t >> 6, lane = t & 63;
    int lr = lane & 15, lg = lane >> 4;
    int R0 = (w >> 1) * 64, C0 = (w & 1) * 64;

    int ar = t >> 1, ah = t & 1;          // A: row, k-half(16 f32)
    int gr_a = row0 + ar;

    f32x4 acc[4][4];
#pragma unroll
    for (int i = 0; i < 4; i++)
#pragma unroll
        for (int j = 0; j < 4; j++) acc[i][j] = (f32x4){0.f, 0.f, 0.f, 0.f};

    for (int it = 0; it < 8; it++) {
        int k0 = it * 32;
        __syncthreads();
        // ---- stage A (convert f32 -> bf16 hi/lo) ----
        {
            float f[16];
            if (gr_a < NN) {
                const float* ap = A + (size_t)gr_a * 256 + k0 + ah * 16;
#pragma unroll
                for (int i = 0; i < 4; i++) {
                    float4 v = *reinterpret_cast<const float4*>(ap + i * 4);
                    f[i * 4 + 0] = v.x; f[i * 4 + 1] = v.y; f[i * 4 + 2] = v.z; f[i * 4 + 3] = v.w;
                }
            } else {
#pragma unroll
                for (int i = 0; i < 16; i++) f[i] = 0.f;
            }
            unsigned hw[8], lw[8];
#pragma unroll
            for (int i = 0; i < 8; i++) {
                ushort_t h0 = f2bf(f[2 * i]), h1v = f2bf(f[2 * i + 1]);
                ushort_t l0 = f2bf(f[2 * i] - bf2f(h0)), l1 = f2bf(f[2 * i + 1] - bf2f(h1v));
                hw[i] = (unsigned)h0 | ((unsigned)h1v << 16);
                lw[i] = (unsigned)l0 | ((unsigned)l1 << 16);
            }
            uint4* dsth = reinterpret_cast<uint4*>(&Ah[ar * LSTR + ah * 16]);
            dsth[0] = make_uint4(hw[0], hw[1], hw[2], hw[3]);
            dsth[1] = make_uint4(hw[4], hw[5], hw[6], hw[7]);
            uint4* dstl = reinterpret_cast<uint4*>(&Al[ar * LSTR + ah * 16]);
            dstl[0] = make_uint4(lw[0], lw[1], lw[2], lw[3]);
            dstl[1] = make_uint4(lw[4], lw[5], lw[6], lw[7]);
        }
        // ---- stage B (pre-split, pre-transposed [n][k]) ----
        {
            int bn = t >> 1, bh2 = t & 1;
            const uint4* sh = reinterpret_cast<const uint4*>(Bht + (size_t)(col0 + bn) * 256 + k0 + bh2 * 16);
            const uint4* sl = reinterpret_cast<const uint4*>(Blt + (size_t)(col0 + bn) * 256 + k0 + bh2 * 16);
            uint4* dh = reinterpret_cast<uint4*>(&Bh[bn * LSTR + bh2 * 16]);
            uint4* dl = reinterpret_cast<uint4*>(&Bl[bn * LSTR + bh2 * 16]);
            dh[0] = sh[0]; dh[1] = sh[1];
            dl[0] = sl[0]; dl[1] = sl[1];
        }
        __syncthreads();
        // ---- fragments + MFMA ----
        short8 bhf[4], blf[4];
#pragma unroll
        for (int ni = 0; ni < 4; ni++) {
            int c = C0 + ni * 16 + lr;
            bhf[ni] = *reinterpret_cast<const short8*>(&Bh[c * LSTR + lg * 8]);
            blf[ni] = *reinterpret_cast<const short8*>(&Bl[c * LSTR + lg * 8]);
        }
#pragma unroll
        for (int mi = 0; mi < 4; mi++) {
            int r = R0 + mi * 16 + lr;
            short8 ahf = *reinterpret_cast<const short8*>(&Ah[r * LSTR + lg * 8]);
            short8 alf = *reinterpret_cast<const short8*>(&Al[r * LSTR + lg * 8]);
#pragma unroll
            for (int ni = 0; ni < 4; ni++) {
                acc[mi][ni] = __builtin_amdgcn_mfma_f32_16x16x32_bf16(ahf, bhf[ni], acc[mi][ni], 0, 0, 0);
                acc[mi][ni] = __builtin_amdgcn_mfma_f32_16x16x32_bf16(alf, bhf[ni], acc[mi][ni], 0, 0, 0);
                acc[mi][ni] = __builtin_amdgcn_mfma_f32_16x16x32_bf16(ahf, blf[ni], acc[mi][ni], 0, 0, 0);
            }
        }
    }

    // ---- epilogue: f16 store + fused alpha dots ----
    int cn[4];
    float sa[4], da[4];
#pragma unroll
    for (int ni = 0; ni < 4; ni++) {
        cn[ni] = col0 + C0 + ni * 16 + lr;
        sa[ni] = attS[cn[ni]];
        da[ni] = attD[cn[ni]];
    }
    int head0 = (col0 + C0) >> 5;
#pragma unroll
    for (int mi = 0; mi < 4; mi++) {
#pragma unroll
        for (int r = 0; r < 4; r++) {
            int gr = row0 + R0 + mi * 16 + lg * 4 + r;
            float v0 = acc[mi][0][r], v1 = acc[mi][1][r];
            float v2 = acc[mi][2][r], v3 = acc[mi][3][r];
            float ps0 = v0 * sa[0] + v1 * sa[1];
            float pd0 = v0 * da[0] + v1 * da[1];
            float ps1 = v2 * sa[2] + v3 * sa[3];
            float pd1 = v2 * da[2] + v3 * da[3];
#pragma unroll
            for (int m = 1; m <= 8; m <<= 1) {
                ps0 += __shfl_xor(ps0, m);
                pd0 += __shfl_xor(pd0, m);
                ps1 += __shfl_xor(ps1, m);
                pd1 += __shfl_xor(pd1, m);
            }
            if (gr < NN) {
                if (lr == 0) {
                    as1[gr * 8 + head0] = ps0;
                    ad1[gr * 8 + head0] = pd0;
                    as1[gr * 8 + head0 + 1] = ps1;
                    ad1[gr * 8 + head0 + 1] = pd1;
                }
                ushort_t* hp = h1h + (size_t)gr * 256;
                hp[cn[0]] = f2h(v0);
                hp[cn[1]] = f2h(v1);
                hp[cn[2]] = f2h(v2);
                hp[cn[3]] = f2h(v3);
            }
        }
    }
}

// ------- softmax stats + weight write, layer 1: one wave/node --------------
__global__ __launch_bounds__(256) void k_soft1(const int* __restrict__ csr_src,
                                               const int* __restrict__ offset,
                                               const int* __restrict__ deg,
                                               const float* __restrict__ as1,
                                               const float* __restrict__ ad1,
                                               float* __restrict__ w1) {
    int wave = (blockIdx.x * blockDim.x + threadIdx.x) >> 6;
    int lane = threadIdx.x & 63;
    if (wave >= NN) return;
    int d = wave;
    int sub = lane >> 3, h = lane & 7;
    float ad = ad1[d * 8 + h];
    int beg = offset[d], cnt = deg[d];
    float m = -1e30f, s = 0.f;
    for (int j = sub; j < cnt; j += 8) {
        int src = csr_src[beg + j];
        float e = as1[src * 8 + h] + ad;
        e = (e > 0.f) ? e : SLOPE * e;
        float mn = fmaxf(m, e);
        s = s * __expf(m - mn) + __expf(e - mn);
        m = mn;
    }
#pragma unroll
    for (int mask = 8; mask <= 32; mask <<= 1) {
        float mo = __shfl_xor(m, mask);
        float so = __shfl_xor(s, mask);
        float mn = fmaxf(m, mo);
        s = s * __expf(m - mn) + so * __expf(mo - mn);
        m = mn;
    }
    float di = 1.f / (s + 1e-16f);
    // phase 2: write normalized weights, CSR order, coalesced
    for (int j = sub; j < cnt; j += 8) {
        int src = csr_src[beg + j];
        float e = as1[src * 8 + h] + ad;
        e = (e > 0.f) ? e : SLOPE * e;
        w1[(size_t)(beg + j) * 8 + h] = __expf(e - m) * di;
    }
}

// ------- aggregate pass, layer 1: 2 waves/node, LDS combine ----------------
__global__ __launch_bounds__(256) void k_agg1(const int* __restrict__ csr_src,
                                              const int* __restrict__ offset,
                                              const int* __restrict__ deg,
                                              const ushort_t* __restrict__ h1h,
                                              const float* __restrict__ w1,
                                              const float* __restrict__ bias1,
                                              ushort_t* __restrict__ h2h) {
    __shared__ float red[2][256];
    int w = threadIdx.x >> 6;
    int lane = threadIdx.x & 63;
    int slot = w >> 1;       // node slot in block (0..1)
    int sub = w & 1;         // edge-half
    int d = blockIdx.x * 2 + slot;   // NN even: all blocks full
    int h = lane >> 3;
    int f0 = lane * 4;
    int beg = offset[d], cnt = deg[d];
    float ax = 0.f, ay = 0.f, az = 0.f, aw = 0.f;
#pragma unroll 4
    for (int j = sub; j < cnt; j += 2) {
        int s = csr_src[beg + j];
        float wg = w1[(size_t)(beg + j) * 8 + h];
        ushort4 hv = *reinterpret_cast<const ushort4*>(h1h + (size_t)s * 256 + f0);
        ax += wg * (float)__builtin_bit_cast(_Float16, hv.x);
        ay += wg * (float)__builtin_bit_cast(_Float16, hv.y);
        az += wg * (float)__builtin_bit_cast(_Float16, hv.z);
        aw += wg * (float)__builtin_bit_cast(_Float16, hv.w);
    }
    if (sub == 1) {
        *reinterpret_cast<float4*>(&red[slot][lane * 4]) = make_float4(ax, ay, az, aw);
    }
    __syncthreads();
    if (sub == 0) {
        float4 r = *reinterpret_cast<const float4*>(&red[slot][lane * 4]);
        float4 b = *reinterpret_cast<const float4*>(bias1 + f0);
        float vx = ax + r.x + b.x;
        float vy = ay + r.y + b.y;
        float vz = az + r.z + b.z;
        float vw = aw + r.w + b.w;
        vx = (vx > 0.f) ? vx : expm1f(vx);
        vy = (vy > 0.f) ? vy : expm1f(vy);
        vz = (vz > 0.f) ? vz : expm1f(vz);
        vw = (vw > 0.f) ? vw : expm1f(vw);
        ushort4 o;
        o.x = f2h(vx); o.y = f2h(vy); o.z = f2h(vz); o.w = f2h(vw);
        *reinterpret_cast<ushort4*>(h2h + (size_t)d * 256 + f0) = o;
    }
}

// ----------------- GEMM2 (MFMA f16): hh(f16) = h2h @ W2; fused alpha2 ------
__global__ __launch_bounds__(256) void k_gemm2(const ushort_t* __restrict__ A,
                                               const ushort_t* __restrict__ Bht,
                                               const ushort_t* __restrict__ Blt,
                                               const float* __restrict__ attS,
                                               const float* __restrict__ attD,
                                               ushort_t* __restrict__ hh,
                                               float* __restrict__ as2,
                                               float* __restrict__ ad2) {
    __shared__ ushort_t Ash[128 * LSTR];
    __shared__ ushort_t Bh[48 * LSTR];
    __shared__ ushort_t Bl[48 * LSTR];
    int row0 = blockIdx.x * 128;
    int t = threadIdx.x;
    int w = t >> 6, lane = t & 63;
    int lr = lane & 15, lg = lane >> 4;
    int R0 = w * 32;

    f32x4 acc[2][3];
#pragma unroll
    for (int i = 0; i < 2; i++)
#pragma unroll
        for (int j = 0; j < 3; j++) acc[i][j] = (f32x4){0.f, 0.f, 0.f, 0.f};

    for (int it = 0; it < 8; it++) {
        int k0 = it * 32;
        __syncthreads();
        // stage A: 128 rows x 32 ushorts = 512 uint4 chunks
#pragma unroll
        for (int i = 0; i < 2; i++) {
            int chunk = t + i * 256;
            int r = chunk >> 2, part = chunk & 3;
            int gr = row0 + r;
            uint4 v = make_uint4(0u, 0u, 0u, 0u);
            if (gr < NN) v = *reinterpret_cast<const uint4*>(A + (size_t)gr * 256 + k0 + part * 8);
            *reinterpret_cast<uint4*>(&Ash[r * LSTR + part * 8]) = v;
        }
        // stage B: 48 rows x 32 ushorts = 192 uint4 chunks
        if (t < 192) {
            int bn = t >> 2, part = t & 3;
            *reinterpret_cast<uint4*>(&Bh[bn * LSTR + part * 8]) =
                *reinterpret_cast<const uint4*>(Bht + (size_t)bn * 256 + k0 + part * 8);
            *reinterpret_cast<uint4*>(&Bl[bn * LSTR + part * 8]) =
                *reinterpret_cast<const uint4*>(Blt + (size_t)bn * 256 + k0 + part * 8);
        }
        __syncthreads();
        half8 bhf[3], blf[3];
#pragma unroll
        for (int ni = 0; ni < 3; ni++) {
            int c = ni * 16 + lr;
            bhf[ni] = *reinterpret_cast<const half8*>(&Bh[c * LSTR + lg * 8]);
            blf[ni] = *reinterpret_cast<const half8*>(&Bl[c * LSTR + lg * 8]);
        }
#pragma unroll
        for (int mi = 0; mi < 2; mi++) {
            int r = R0 + mi * 16 + lr;
            half8 af = *reinterpret_cast<const half8*>(&Ash[r * LSTR + lg * 8]);
#pragma unroll
            for (int ni = 0; ni < 3; ni++) {
                acc[mi][ni] = __builtin_amdgcn_mfma_f32_16x16x32_f16(af, bhf[ni], acc[mi][ni], 0, 0, 0);
                acc[mi][ni] = __builtin_amdgcn_mfma_f32_16x16x32_f16(af, blf[ni], acc[mi][ni], 0, 0, 0);
            }
        }
    }

    // epilogue: store hh(f16) + fused alpha2
    int cn[3];
    float sa[3], da[3];
#pragma unroll
    for (int ni = 0; ni < 3; ni++) {
        cn[ni] = ni * 16 + lr;
        sa[ni] = (cn[ni] < NCLS) ? attS[cn[ni]] : 0.f;
        da[ni] = (cn[ni] < NCLS) ? attD[cn[ni]] : 0.f;
    }
#pragma unroll
    for (int mi = 0; mi < 2; mi++) {
#pragma unroll
        for (int r = 0; r < 4; r++) {
            int gr = row0 + R0 + mi * 16 + lg * 4 + r;
            float v0 = acc[mi][0][r], v1 = acc[mi][1][r], v2 = acc[mi][2][r];
            float ps = v0 * sa[0] + v1 * sa[1] + v2 * sa[2];
            float pd = v0 * da[0] + v1 * da[1] + v2 * da[2];
#pragma unroll
            for (int m = 1; m <= 8; m <<= 1) {
                ps += __shfl_xor(ps, m);
                pd += __shfl_xor(pd, m);
            }
            if (gr < NN) {
                if (lr == 0) { as2[gr] = ps; ad2[gr] = pd; }
                ushort_t* hp = hh + (size_t)gr * NCLS;
                if (cn[0] < NCLS) hp[cn[0]] = f2h(v0);
                if (cn[1] < NCLS) hp[cn[1]] = f2h(v1);
                if (cn[2] < NCLS) hp[cn[2]] = f2h(v2);
            }
        }
    }
}

// ------- softmax stats + weight write, layer 2: one wave/node --------------
__global__ __launch_bounds__(256) void k_soft2(const int* __restrict__ csr_src,
                                               const int* __restrict__ offset,
                                               const int* __restrict__ deg,
                                               const float* __restrict__ as2,
                                               const float* __restrict__ ad2,
                                               float* __restrict__ w2) {
    int wave = (blockIdx.x * blockDim.x + threadIdx.x) >> 6;
    int lane = threadIdx.x & 63;
    if (wave >= NN) return;
    int d = wave;
    float ad = ad2[d];
    int beg = offset[d], cnt = deg[d];
    float m = -1e30f, s = 0.f;
    for (int j = lane; j < cnt; j += 64) {
        int src = csr_src[beg + j];
        float e = as2[src] + ad;
        e = (e > 0.f) ? e : SLOPE * e;
        float mn = fmaxf(m, e);
        s = s * __expf(m - mn) + __expf(e - mn);
        m = mn;
    }
#pragma unroll
    for (int mask = 1; mask <= 32; mask <<= 1) {
        float mo = __shfl_xor(m, mask);
        float so = __shfl_xor(s, mask);
        float mn = fmaxf(m, mo);
        s = s * __expf(m - mn) + so * __expf(mo - mn);
        m = mn;
    }
    float di = 1.f / (s + 1e-16f);
    for (int j = lane; j < cnt; j += 64) {
        int src = csr_src[beg + j];
        float e = as2[src] + ad;
        e = (e > 0.f) ? e : SLOPE * e;
        w2[beg + j] = __expf(e - m) * di;
    }
}

// ------- aggregate pass, layer 2: 3 edges in flight, 20 lanes each ---------
__global__ __launch_bounds__(256) void k_agg2(const int* __restrict__ csr_src,
                                              const int* __restrict__ offset,
                                              const int* __restrict__ deg,
                                              const ushort_t* __restrict__ hh,
                                              const float* __restrict__ w2,
                                              const float* __restrict__ bias2,
                                              float* __restrict__ out) {
    int wave = (blockIdx.x * blockDim.x + threadIdx.x) >> 6;
    int lane = threadIdx.x & 63;
    if (wave >= NN) return;
    int d = wave;
    int es = lane / 20;       // edge slot 0..2 (3 = idle)
    int ch = lane % 20;       // uint chunk -> classes 2ch, 2ch+1
    int beg = offset[d], cnt = deg[d];
    float a0 = 0.f, a1 = 0.f;
    for (int j0 = 0; j0 < cnt; j0 += 3) {
        int j = j0 + es;
        if (es < 3 && j < cnt) {
            int s = csr_src[beg + j];
            float w = w2[beg + j];
            unsigned v = *reinterpret_cast<const unsigned*>(hh + (size_t)s * NCLS + ch * 2);
            a0 += w * (float)__builtin_bit_cast(_Float16, (ushort_t)(v & 0xFFFFu));
            a1 += w * (float)__builtin_bit_cast(_Float16, (ushort_t)(v >> 16));
        }
    }
    float t0 = __shfl(a0, lane + 20);
    float t1 = __shfl(a0, lane + 40);
    float u0 = __shfl(a1, lane + 20);
    float u1 = __shfl(a1, lane + 40);
    if (lane < 20) {
        float2 o;
        o.x = a0 + t0 + t1 + bias2[ch * 2];
        o.y = a1 + u0 + u1 + bias2[ch * 2 + 1];
        *reinterpret_cast<float2*>(out + (size_t)d * NCLS + ch * 2) = o;
    }
}

extern "C" void kernel_launch(void* const* d_in, const int* in_sizes, int n_in,
                              void* d_out, int out_size, void* d_ws, size_t ws_size,
                              hipStream_t stream) {
    const float* x      = (const float*)d_in[0];
    const int* ei       = (const int*)d_in[1];   // int64 in ref -> int32 on device
    const float* W1     = (const float*)d_in[2];
    const float* att_s1 = (const float*)d_in[3];
    const float* att_d1 = (const float*)d_in[4];
    const float* bias1  = (const float*)d_in[5];
    const float* W2     = (const float*)d_in[6];
    const float* att_s2 = (const float*)d_in[7];
    const float* att_d2 = (const float*)d_in[8];
    const float* bias2  = (const float*)d_in[9];
    float* out = (float*)d_out;

    char* ws = (char*)d_ws;
    size_t off = 0;
    auto alloc = [&](size_t bytes) -> void* {
        void* p = ws + off;
        off = (off + bytes + 255) & ~(size_t)255;
        return p;
    };
    ushort_t* h1h = (ushort_t*)alloc((size_t)NN * 256 * 2);
    ushort_t* h2h = (ushort_t*)alloc((size_t)NN * 256 * 2);
    ushort_t* hh  = (ushort_t*)alloc((size_t)NN * NCLS * 2);
    float* as1  = (float*)alloc((size_t)NN * 8 * 4);
    float* ad1  = (float*)alloc((size_t)NN * 8 * 4);
    float* as2  = (float*)alloc((size_t)NN * 4);
    float* ad2  = (float*)alloc((size_t)NN * 4);
    float* w1   = (float*)alloc((size_t)ETOT * 8 * 4);
    float* w2   = (float*)alloc((size_t)ETOT * 4);
    int* deg    = (int*)alloc((size_t)NN * 4);
    int* offs   = (int*)alloc((size_t)(NN + 1) * 4);
    int* cursor = (int*)alloc((size_t)NN * 4);
    int* csr    = (int*)alloc((size_t)ETOT * 4);
    int* bsum   = (int*)alloc(4096);
    ushort_t* W1ht = (ushort_t*)alloc((size_t)256 * 256 * 2);
    ushort_t* W1lt = (ushort_t*)alloc((size_t)256 * 256 * 2);
    ushort_t* W2ht = (ushort_t*)alloc((size_t)48 * 256 * 2);
    ushort_t* W2lt = (ushort_t*)alloc((size_t)48 * 256 * 2);

    // CSR prep (scatter deferred into fused launch)
    k_deg_init<<<(NN + 255) / 256, 256, 0, stream>>>(deg);
    k_hist<<<(NE + 255) / 256, 256, 0, stream>>>(ei, deg);
    k_blocksum<<<NBLK, SCAN_B, 0, stream>>>(deg, bsum);
    k_scan_bsums<<<1, 1024, 0, stream>>>(bsum, NBLK);
    k_offsets<<<NBLK, SCAN_B, 0, stream>>>(deg, bsum, offs, cursor, csr);

    // Layer 1: fused GEMM1 + scatter, then softmax weights, then aggregate
    k_splitW<<<256, 256, 0, stream>>>(W1, W1ht, W1lt);
    k_gemm1s<<<GB1 + SCB, 256, 0, stream>>>(x, W1ht, W1lt, att_s1, att_d1, h1h, as1, ad1,
                                            ei, cursor, csr);
    k_soft1<<<(NN + 3) / 4, 256, 0, stream>>>(csr, offs, deg, as1, ad1, w1);
    k_agg1<<<NN / 2, 256, 0, stream>>>(csr, offs, deg, h1h, w1, bias1, h2h);

    // Layer 2
    k_splitW2<<<48, 256, 0, stream>>>(W2, W2ht, W2lt);
    k_gemm2<<<(NN + 127) / 128, 256, 0, stream>>>(h2h, W2ht, W2lt, att_s2, att_d2, hh, as2, ad2);
    k_soft2<<<(NN + 3) / 4, 256, 0, stream>>>(csr, offs, deg, as2, ad2, w2);
    k_agg2<<<(NN + 3) / 4, 256, 0, stream>>>(csr, offs, deg, hh, w2, bias2, out);
}